// Round 9
// baseline (540.804 us; speedup 1.0000x reference)
//
#include <hip/hip_runtime.h>
#include <stdint.h>

#define N_NODES 131072
#define HDIM 128

typedef __bf16 bf16x8 __attribute__((ext_vector_type(8)));
typedef float f32x4 __attribute__((ext_vector_type(4)));
typedef unsigned short us8 __attribute__((ext_vector_type(8)));
typedef unsigned short ushort_t;

__device__ __forceinline__ float bf2f(ushort_t u) {
    union { float f; uint32_t i; } v; v.i = ((uint32_t)u) << 16; return v.f;
}
__device__ __forceinline__ ushort_t f2bf(float f) {
    union { float f; uint32_t i; } v; v.f = f;
    uint32_t i = v.i;
    return (ushort_t)((i + 0x7FFFu + ((i >> 16) & 1u)) >> 16);  // RNE
}

// fast sigmoid / tanh via v_exp_f32 + v_rcp_f32 (bf16-accurate)
__device__ __forceinline__ float fsig(float x) {
    return __builtin_amdgcn_rcpf(1.0f + __expf(-x));
}
__device__ __forceinline__ float ftanh(float y) {
    float yc = fminf(fmaxf(y, -15.0f), 15.0f);
    float e = __expf(2.0f * yc);
    return (e - 1.0f) * __builtin_amdgcn_rcpf(e + 1.0f);
}

// XCD-temporal block swizzle [verified R6: FETCH 264->34 MB]
template<int NC>
__device__ __forceinline__ void swz(int b, int& m, int& c) {
    int mhi = b / (8 * NC);
    int rem = b - mhi * (8 * NC);
    c = rem >> 3;
    m = mhi * 8 + (rem & 7);
}

// ---------------------------------------------------------------------------
// prep: fp32->bf16 GRU weight conversion (294912 elems -> 1152 blocks)
// ---------------------------------------------------------------------------
__global__ __launch_bounds__(256) void prep_weights(
    const float* __restrict__ w_f1, const float* __restrict__ w_b1,
    const float* __restrict__ w_f2, const float* __restrict__ w_b2,
    ushort_t* __restrict__ PWF1, ushort_t* __restrict__ PWB1,
    ushort_t* __restrict__ PWF2, ushort_t* __restrict__ PWB2)
{
    int idx = blockIdx.x * 256 + threadIdx.x;
    if (idx < 49152) {
        PWF1[idx] = f2bf(w_f1[idx]);
    } else if (idx < 98304) {
        int j = idx - 49152;  PWB1[j] = f2bf(w_b1[j]);
    } else if (idx < 196608) {
        int j = idx - 98304;  PWF2[j] = f2bf(w_f2[j]);
    } else if (idx < 294912) {
        int j = idx - 196608; PWB2[j] = f2bf(w_b2[j]);
    }
}

// ---------------------------------------------------------------------------
// prep_M (1 block, LDS-staged, float4 rows): collapse the linear GCN tail.
//   T1 = w_g2 @ w_fc [128,10]; M = w_g1 @ T1 [256,10] -> M16 [16,256] bf16;
//   cc1 = b_g1 @ T1 (cc[0..9]); cc2 = b_g2 @ w_fc + b_fc (cc[16..25])
// R8 version was ~100+ us: scalar strided reads, 64 lines/instr, one CU.
// ---------------------------------------------------------------------------
__global__ __launch_bounds__(256) void prep_M(
    const float* __restrict__ w_g1, const float* __restrict__ b_g1,
    const float* __restrict__ w_g2, const float* __restrict__ b_g2,
    const float* __restrict__ w_fc, const float* __restrict__ b_fc,
    ushort_t* __restrict__ M16, float* __restrict__ cc)
{
    __shared__ float wfc_s[640];
    __shared__ float T1[128][10];
    const int t = threadIdx.x;
    for (int i = t; i < 640; i += 256) wfc_s[i] = w_fc[i];
    __syncthreads();
    if (t < 128) {
        float s[10];
        #pragma unroll
        for (int j = 0; j < 10; ++j) s[j] = 0.0f;
        const float4* row = (const float4*)(w_g2 + t * 64);
        #pragma unroll
        for (int k4 = 0; k4 < 16; ++k4) {
            float4 v = row[k4];
            #pragma unroll
            for (int j = 0; j < 10; ++j)
                s[j] += v.x * wfc_s[(k4 * 4 + 0) * 10 + j] + v.y * wfc_s[(k4 * 4 + 1) * 10 + j]
                      + v.z * wfc_s[(k4 * 4 + 2) * 10 + j] + v.w * wfc_s[(k4 * 4 + 3) * 10 + j];
        }
        #pragma unroll
        for (int j = 0; j < 10; ++j) T1[t][j] = s[j];
    }
    __syncthreads();
    float m[10];
    #pragma unroll
    for (int j = 0; j < 10; ++j) m[j] = 0.0f;
    const float4* row1 = (const float4*)(w_g1 + t * 128);
    #pragma unroll 4
    for (int k4 = 0; k4 < 32; ++k4) {
        float4 v = row1[k4];
        #pragma unroll
        for (int j = 0; j < 10; ++j)
            m[j] += v.x * T1[k4 * 4 + 0][j] + v.y * T1[k4 * 4 + 1][j]
                  + v.z * T1[k4 * 4 + 2][j] + v.w * T1[k4 * 4 + 3][j];
    }
    #pragma unroll
    for (int j = 0; j < 16; ++j)
        M16[j * 256 + t] = (j < 10) ? f2bf(m[j]) : (ushort_t)0;
    if (t < 10) {
        float s1 = 0.0f;
        for (int k2 = 0; k2 < 128; ++k2) s1 += b_g1[k2] * T1[k2][t];
        cc[t] = s1;
        float s2 = 0.0f;
        for (int k3 = 0; k3 < 64; ++k3) s2 += b_g2[k3] * wfc_s[k3 * 10 + t];
        cc[16 + t] = s2 + b_fc[t];
    }
}

// x fp32 [N,128] -> bf16, 8 elems/thread
__global__ __launch_bounds__(256) void xconv(
    const float* __restrict__ x, ushort_t* __restrict__ xb)
{
    int idx = blockIdx.x * 256 + threadIdx.x;   // N*16 chunks
    const float* s = x + (size_t)idx * 8;
    float4 f0 = ((const float4*)s)[0];
    float4 f1 = ((const float4*)s)[1];
    us8 t;
    t[0] = f2bf(f0.x); t[1] = f2bf(f0.y); t[2] = f2bf(f0.z); t[3] = f2bf(f0.w);
    t[4] = f2bf(f1.x); t[5] = f2bf(f1.y); t[6] = f2bf(f1.z); t[7] = f2bf(f1.w);
    *(us8*)&xb[(size_t)idx * 8] = t;
}

// ---------------------------------------------------------------------------
// Fused GRU GEMM v3: LDS-free, barrier-free register-direct MFMA streaming.
// Each lane loads its A/B fragments (16B) straight from row-major global;
// compiler pipelines loads vs MFMA with fine-grained vmcnt (no s_barrier).
// A shared across the 8 combos of an m-tile via L2 (XCD swizzle).
// ---------------------------------------------------------------------------
template<int K>
__global__ __launch_bounds__(256) void gru_gemm3(
    const ushort_t* __restrict__ A,      // [N,K] bf16
    const ushort_t* __restrict__ Wf,     // [384,K] bf16
    const ushort_t* __restrict__ Wb,     // [384,K] bf16
    const float* __restrict__ bi_f, const float* __restrict__ bh_f,
    const float* __restrict__ bi_b, const float* __restrict__ bh_b,
    ushort_t* __restrict__ Hout)         // [N,256] bf16
{
    const int tid = threadIdx.x;
    int mt, comb;
    swz<8>(blockIdx.x, mt, comb);
    const int m0 = mt * 128;
    const int dir = comb >> 2;
    const int j0 = (comb & 3) * 32;
    const ushort_t* W = dir ? Wb : Wf;
    const float* b_ih = dir ? bi_b : bi_f;
    const float* b_hh = dir ? bh_b : bh_f;
    const int coloff = dir << 7;

    const int wv = tid >> 6, lane = tid & 63;
    const int lr = lane & 15, lq = lane >> 4;

    // A-frag rows: this wave's own 32 rows. A[m=lr][k=lq*8+j] layout [m120]
    const ushort_t* a0p = A + (size_t)(m0 + wv * 32 + lr) * K + lq * 8;
    const ushort_t* a1p = a0p + (size_t)16 * K;
    // B-frag rows: W[(gate*128 + j0 + ct*16 + lr)][k]
    const ushort_t* b00 = W + (size_t)(j0 + lr) * K + lq * 8;

    f32x4 acc[3][2][2];
    #pragma unroll
    for (int g = 0; g < 3; ++g)
        #pragma unroll
        for (int rt = 0; rt < 2; ++rt)
            #pragma unroll
            for (int ct = 0; ct < 2; ++ct)
                #pragma unroll
                for (int e = 0; e < 4; ++e) acc[g][rt][ct][e] = 0.0f;

    #pragma unroll 4
    for (int kk = 0; kk < K; kk += 32) {
        bf16x8 a0 = *(const bf16x8*)(a0p + kk);
        bf16x8 a1 = *(const bf16x8*)(a1p + kk);
        #pragma unroll
        for (int g = 0; g < 3; ++g) {
            #pragma unroll
            for (int ct = 0; ct < 2; ++ct) {
                bf16x8 b = *(const bf16x8*)(b00 + (size_t)(g * 128 + ct * 16) * K + kk);
                acc[g][0][ct] = __builtin_amdgcn_mfma_f32_16x16x32_bf16(a0, b, acc[g][0][ct], 0, 0, 0);
                acc[g][1][ct] = __builtin_amdgcn_mfma_f32_16x16x32_bf16(a1, b, acc[g][1][ct], 0, 0, 0);
            }
        }
    }

    // epilogue: C/D layout col=lane&15, row=(lane>>4)*4+reg [m89/m91]
    #pragma unroll
    for (int ct = 0; ct < 2; ++ct) {
        const int j = j0 + ct * 16 + lr;
        const float br  = b_ih[j] + b_hh[j];
        const float bz  = b_ih[HDIM + j] + b_hh[HDIM + j];
        const float bn  = b_ih[2 * HDIM + j];
        const float bhn = b_hh[2 * HDIM + j];
        #pragma unroll
        for (int rt = 0; rt < 2; ++rt) {
            #pragma unroll
            for (int r = 0; r < 4; ++r) {
                const int row = m0 + wv * 32 + rt * 16 + lq * 4 + r;
                float rg = fsig(acc[0][rt][ct][r] + br);
                float zg = fsig(acc[1][rt][ct][r] + bz);
                float ng = ftanh(acc[2][rt][ct][r] + bn + rg * bhn);
                Hout[(size_t)row * 256 + coloff + j] = f2bf((1.0f - zg) * ng);
            }
        }
    }
}

// ---------------------------------------------------------------------------
// zgemm v2: Zc = h2 @ M16^T, LDS-free/barrier-free, B in registers.
// ---------------------------------------------------------------------------
__global__ __launch_bounds__(256) void zgemm(
    const ushort_t* __restrict__ A,    // h2 [N,256] bf16
    const ushort_t* __restrict__ M16,  // [16,256] bf16
    float* __restrict__ Zc)            // [N,10] fp32
{
    const int tid = threadIdx.x;
    const int m0 = blockIdx.x * 128;
    const int wv = tid >> 6, lane = tid & 63;
    const int lr = lane & 15, lq = lane >> 4;

    bf16x8 bfrag[8];
    #pragma unroll
    for (int s = 0; s < 8; ++s)
        bfrag[s] = *(const bf16x8*)&M16[lr * 256 + s * 32 + lq * 8];

    const ushort_t* a0p = A + (size_t)(m0 + wv * 32 + lr) * 256 + lq * 8;
    const ushort_t* a1p = a0p + 16 * 256;

    f32x4 acc[2];
    #pragma unroll
    for (int e = 0; e < 4; ++e) { acc[0][e] = 0.0f; acc[1][e] = 0.0f; }

    #pragma unroll
    for (int s = 0; s < 8; ++s) {
        bf16x8 a0 = *(const bf16x8*)(a0p + s * 32);
        bf16x8 a1 = *(const bf16x8*)(a1p + s * 32);
        acc[0] = __builtin_amdgcn_mfma_f32_16x16x32_bf16(a0, bfrag[s], acc[0], 0, 0, 0);
        acc[1] = __builtin_amdgcn_mfma_f32_16x16x32_bf16(a1, bfrag[s], acc[1], 0, 0, 0);
    }

    if (lr < 10) {
        #pragma unroll
        for (int rt = 0; rt < 2; ++rt)
            #pragma unroll
            for (int r = 0; r < 4; ++r) {
                int row = m0 + wv * 32 + rt * 16 + lq * 4 + r;
                Zc[(size_t)row * 10 + lr] = acc[rt][r];
            }
    }
}

// ---------------------------------------------------------------------------
// st5: fused double GCN aggregation (5-point stencil) + bias corrections.
// v_i = d_i * sum_j d_j^2 * (sum_k d_k z_k) + d_i*dsum_i*cc1[c] + cc2[c]
// ---------------------------------------------------------------------------
__device__ __forceinline__ float dcoef(int i) {
    return (i == 0 || i == N_NODES - 1) ? 0.70710678118654752f : 0.57735026918962576f;
}
__global__ __launch_bounds__(256) void st5(
    const float* __restrict__ z, float* __restrict__ out,
    const float* __restrict__ cc)
{
    int idx = blockIdx.x * 256 + threadIdx.x;   // N*16
    int i = idx >> 4, c = idx & 15;
    if (c >= 10) return;
    float d_i = dcoef(i);
    float accv = 0.0f, dsum = d_i;
    #pragma unroll
    for (int oj = -1; oj <= 1; ++oj) {
        int j = i + oj;
        if (j < 0 || j >= N_NODES) continue;
        float dj = dcoef(j);
        if (oj != 0) dsum += dj;
        float wj = 0.0f;
        #pragma unroll
        for (int ok = -1; ok <= 1; ++ok) {
            int k = j + ok;
            if (k < 0 || k >= N_NODES) continue;
            wj += dcoef(k) * z[(size_t)k * 10 + c];
        }
        accv += dj * dj * wj;
    }
    out[(size_t)i * 10 + c] = d_i * accv + d_i * dsum * cc[c] + cc[16 + c];
}

extern "C" void kernel_launch(void* const* d_in, const int* in_sizes, int n_in,
                              void* d_out, int out_size, void* d_ws, size_t ws_size,
                              hipStream_t stream) {
    const float* x     = (const float*)d_in[0];
    const float* w_f1  = (const float*)d_in[1];
    const float* bi_f1 = (const float*)d_in[2];
    const float* bh_f1 = (const float*)d_in[3];
    const float* w_b1  = (const float*)d_in[4];
    const float* bi_b1 = (const float*)d_in[5];
    const float* bh_b1 = (const float*)d_in[6];
    const float* w_f2  = (const float*)d_in[7];
    const float* bi_f2 = (const float*)d_in[8];
    const float* bh_f2 = (const float*)d_in[9];
    const float* w_b2  = (const float*)d_in[10];
    const float* bi_b2 = (const float*)d_in[11];
    const float* bh_b2 = (const float*)d_in[12];
    const float* w_g1  = (const float*)d_in[13];
    const float* b_g1  = (const float*)d_in[14];
    const float* w_g2  = (const float*)d_in[15];
    const float* b_g2  = (const float*)d_in[16];
    const float* w_fc  = (const float*)d_in[17];
    const float* b_fc  = (const float*)d_in[18];

    char* ws = (char*)d_ws;
    ushort_t* h1   = (ushort_t*)(ws);                    // [N,256] bf16, dies after layer2
    ushort_t* xb   = (ushort_t*)(ws + 67108864);         // [N,128] bf16 x, dies after layer1
    ushort_t* h2   = (ushort_t*)(ws + 67108864);         // [N,256] bf16, overwrites dead xb
    float*    Zc   = (float*)(ws);                       // [N,10] fp32, reuse dead h1
    ushort_t* PWF1 = (ushort_t*)(ws + 134217728);        // [384,128] bf16
    ushort_t* PWB1 = PWF1 + 49152;
    ushort_t* PWF2 = PWB1 + 49152;                       // [384,256] bf16
    ushort_t* PWB2 = PWF2 + 98304;
    ushort_t* M16  = PWB2 + 98304;                       // [16,256] bf16
    float*    cc   = (float*)(M16 + 4096);               // cc1[0..9], cc2[16..25]

    prep_weights<<<1152, 256, 0, stream>>>(w_f1, w_b1, w_f2, w_b2,
                                           PWF1, PWB1, PWF2, PWB2);
    prep_M<<<1, 256, 0, stream>>>(w_g1, b_g1, w_g2, b_g2, w_fc, b_fc, M16, cc);
    xconv<<<N_NODES * 16 / 256, 256, 0, stream>>>(x, xb);

    gru_gemm3<128><<<N_NODES / 128 * 8, 256, 0, stream>>>(
        xb, PWF1, PWB1, bi_f1, bh_f1, bi_b1, bh_b1, h1);
    gru_gemm3<256><<<N_NODES / 128 * 8, 256, 0, stream>>>(
        h1, PWF2, PWB2, bi_f2, bh_f2, bi_b2, bh_b2, h2);

    zgemm<<<N_NODES / 128, 256, 0, stream>>>(h2, M16, Zc);
    st5<<<N_NODES * 16 / 256, 256, 0, stream>>>(Zc, (float*)d_out, cc);
}

// Round 10
// 295.956 us; speedup vs baseline: 1.8273x; 1.8273x over previous
//
#include <hip/hip_runtime.h>
#include <stdint.h>

#define N_NODES 131072
#define HDIM 128

typedef __bf16 bf16x8 __attribute__((ext_vector_type(8)));
typedef float f32x4 __attribute__((ext_vector_type(4)));
typedef unsigned short us8 __attribute__((ext_vector_type(8)));
typedef unsigned short ushort_t;

__device__ __forceinline__ float bf2f(ushort_t u) {
    union { float f; uint32_t i; } v; v.i = ((uint32_t)u) << 16; return v.f;
}
__device__ __forceinline__ ushort_t f2bf(float f) {
    union { float f; uint32_t i; } v; v.f = f;
    uint32_t i = v.i;
    return (ushort_t)((i + 0x7FFFu + ((i >> 16) & 1u)) >> 16);  // RNE
}

// async global->LDS 16B DMA: LDS dest = wave-uniform base + lane*16
__device__ __forceinline__ void gll16(const ushort_t* g, ushort_t* l) {
    __builtin_amdgcn_global_load_lds(
        (const __attribute__((address_space(1))) uint32_t*)g,
        (__attribute__((address_space(3))) uint32_t*)l, 16, 0, 0);
}

// BK=64 rot swizzle: LDS row r slot c holds global chunk (c+r)&7 (16B chunks)
// [verified R7: SQ_LDS_BANK_CONFLICT -> 0]
__device__ __forceinline__ bf16x8 ldsw(const ushort_t* base, int R, int g) {
    return *(const bf16x8*)&base[R * 64 + (((g - R) & 7) << 3)];
}

// fast sigmoid / tanh via v_exp_f32 + v_rcp_f32 (bf16-accurate)
__device__ __forceinline__ float fsig(float x) {
    return __builtin_amdgcn_rcpf(1.0f + __expf(-x));
}
__device__ __forceinline__ float ftanh(float y) {
    float yc = fminf(fmaxf(y, -15.0f), 15.0f);
    float e = __expf(2.0f * yc);
    return (e - 1.0f) * __builtin_amdgcn_rcpf(e + 1.0f);
}

// XCD-temporal block swizzle [verified R6: FETCH 264->34 MB]
template<int NC>
__device__ __forceinline__ void swz(int b, int& m, int& c) {
    int mhi = b / (8 * NC);
    int rem = b - mhi * (8 * NC);
    c = rem >> 3;
    m = mhi * 8 + (rem & 7);
}

// ---------------------------------------------------------------------------
// prep: fp32->bf16 GRU weight conversion (294912 elems -> 1152 blocks)
// ---------------------------------------------------------------------------
__global__ __launch_bounds__(256) void prep_weights(
    const float* __restrict__ w_f1, const float* __restrict__ w_b1,
    const float* __restrict__ w_f2, const float* __restrict__ w_b2,
    ushort_t* __restrict__ PWF1, ushort_t* __restrict__ PWB1,
    ushort_t* __restrict__ PWF2, ushort_t* __restrict__ PWB2)
{
    int idx = blockIdx.x * 256 + threadIdx.x;
    if (idx < 49152) {
        PWF1[idx] = f2bf(w_f1[idx]);
    } else if (idx < 98304) {
        int j = idx - 49152;  PWB1[j] = f2bf(w_b1[j]);
    } else if (idx < 196608) {
        int j = idx - 98304;  PWF2[j] = f2bf(w_f2[j]);
    } else if (idx < 294912) {
        int j = idx - 196608; PWB2[j] = f2bf(w_b2[j]);
    }
}

// ---------------------------------------------------------------------------
// prep_M (1 block, LDS-staged, float4 rows) [verified R9: tail total ~30 us]
//   T1 = w_g2 @ w_fc [128,10]; M = w_g1 @ T1 [256,10] -> M16 [16,256] bf16;
//   cc1 = b_g1 @ T1 (cc[0..9]); cc2 = b_g2 @ w_fc + b_fc (cc[16..25])
// ---------------------------------------------------------------------------
__global__ __launch_bounds__(256) void prep_M(
    const float* __restrict__ w_g1, const float* __restrict__ b_g1,
    const float* __restrict__ w_g2, const float* __restrict__ b_g2,
    const float* __restrict__ w_fc, const float* __restrict__ b_fc,
    ushort_t* __restrict__ M16, float* __restrict__ cc)
{
    __shared__ float wfc_s[640];
    __shared__ float T1[128][10];
    const int t = threadIdx.x;
    for (int i = t; i < 640; i += 256) wfc_s[i] = w_fc[i];
    __syncthreads();
    if (t < 128) {
        float s[10];
        #pragma unroll
        for (int j = 0; j < 10; ++j) s[j] = 0.0f;
        const float4* row = (const float4*)(w_g2 + t * 64);
        #pragma unroll
        for (int k4 = 0; k4 < 16; ++k4) {
            float4 v = row[k4];
            #pragma unroll
            for (int j = 0; j < 10; ++j)
                s[j] += v.x * wfc_s[(k4 * 4 + 0) * 10 + j] + v.y * wfc_s[(k4 * 4 + 1) * 10 + j]
                      + v.z * wfc_s[(k4 * 4 + 2) * 10 + j] + v.w * wfc_s[(k4 * 4 + 3) * 10 + j];
        }
        #pragma unroll
        for (int j = 0; j < 10; ++j) T1[t][j] = s[j];
    }
    __syncthreads();
    float m[10];
    #pragma unroll
    for (int j = 0; j < 10; ++j) m[j] = 0.0f;
    const float4* row1 = (const float4*)(w_g1 + t * 128);
    #pragma unroll 4
    for (int k4 = 0; k4 < 32; ++k4) {
        float4 v = row1[k4];
        #pragma unroll
        for (int j = 0; j < 10; ++j)
            m[j] += v.x * T1[k4 * 4 + 0][j] + v.y * T1[k4 * 4 + 1][j]
                  + v.z * T1[k4 * 4 + 2][j] + v.w * T1[k4 * 4 + 3][j];
    }
    #pragma unroll
    for (int j = 0; j < 16; ++j)
        M16[j * 256 + t] = (j < 10) ? f2bf(m[j]) : (ushort_t)0;
    if (t < 10) {
        float s1 = 0.0f;
        for (int k2 = 0; k2 < 128; ++k2) s1 += b_g1[k2] * T1[k2][t];
        cc[t] = s1;
        float s2 = 0.0f;
        for (int k3 = 0; k3 < 64; ++k3) s2 += b_g2[k3] * wfc_s[k3 * 10 + t];
        cc[16 + t] = s2 + b_fc[t];
    }
}

// x fp32 [N,128] -> bf16, 8 elems/thread
__global__ __launch_bounds__(256) void xconv(
    const float* __restrict__ x, ushort_t* __restrict__ xb)
{
    int idx = blockIdx.x * 256 + threadIdx.x;   // N*16 chunks
    const float* s = x + (size_t)idx * 8;
    float4 f0 = ((const float4*)s)[0];
    float4 f1 = ((const float4*)s)[1];
    us8 t;
    t[0] = f2bf(f0.x); t[1] = f2bf(f0.y); t[2] = f2bf(f0.z); t[3] = f2bf(f0.w);
    t[4] = f2bf(f1.x); t[5] = f2bf(f1.y); t[6] = f2bf(f1.z); t[7] = f2bf(f1.w);
    *(us8*)&xb[(size_t)idx * 8] = t;
}

// ---------------------------------------------------------------------------
// Fused GRU GEMM (both directions), BK=64, 28KB LDS -> 5 blocks/CU.
// [R7-verified: 72 us, MfmaUtil 31%, conflicts 0. R9's LDS-free variant was
//  255 us latency-bound — LDS staging IS the latency-hiding mechanism.]
// ---------------------------------------------------------------------------
template<int K>
__global__ __launch_bounds__(256, 5) void gru_gemm2(
    const ushort_t* __restrict__ A,      // [N,K] bf16
    const ushort_t* __restrict__ Wf,     // [384,K] bf16
    const ushort_t* __restrict__ Wb,     // [384,K] bf16
    const float* __restrict__ bi_f, const float* __restrict__ bh_f,
    const float* __restrict__ bi_b, const float* __restrict__ bh_b,
    ushort_t* __restrict__ Hout)         // [N,256] bf16
{
    __shared__ ushort_t As[128 * 64];    // 16 KB
    __shared__ ushort_t Bs[96 * 64];     // 12 KB
    const int tid = threadIdx.x;
    int mt, comb;
    swz<8>(blockIdx.x, mt, comb);
    const int m0 = mt * 128;
    const int dir = comb >> 2;
    const int j0 = (comb & 3) * 32;
    const ushort_t* W = dir ? Wb : Wf;
    const float* b_ih = dir ? bi_b : bi_f;
    const float* b_hh = dir ? bh_b : bh_f;
    const int coloff = dir << 7;

    const int wv = tid >> 6, lane = tid & 63;
    const int lr = lane & 15, lq = lane >> 4;
    const int tr = tid >> 3, tc = tid & 7;      // 32 rows x 8 chunks per pass
    const int sc = ((tr + tc) & 7) << 3;        // rotated source chunk (shorts)

    f32x4 acc[3][2][2];
    #pragma unroll
    for (int g = 0; g < 3; ++g)
        #pragma unroll
        for (int rt = 0; rt < 2; ++rt)
            #pragma unroll
            for (int ct = 0; ct < 2; ++ct)
                #pragma unroll
                for (int e = 0; e < 4; ++e) acc[g][rt][ct][e] = 0.0f;

    for (int t = 0; t < K / 64; ++t) {
        const int k0 = t * 64;
        const ushort_t* ga = A + (size_t)(m0 + tr) * K + k0 + sc;
        #pragma unroll
        for (int i = 0; i < 4; ++i)
            gll16(ga + (size_t)i * 32 * K, &As[(i * 256 + tid) * 8]);
        #pragma unroll
        for (int i = 0; i < 3; ++i) {
            int wr = (i << 7) + j0 + tr;
            gll16(W + (size_t)wr * K + k0 + sc, &Bs[(i * 256 + tid) * 8]);
        }
        __syncthreads();
        #pragma unroll
        for (int kk = 0; kk < 64; kk += 32) {
            const int g8 = (kk >> 3) + lq;
            bf16x8 a0 = ldsw(As, wv * 32 + lr, g8);
            bf16x8 a1 = ldsw(As, wv * 32 + 16 + lr, g8);
            #pragma unroll
            for (int g = 0; g < 3; ++g) {
                #pragma unroll
                for (int ct = 0; ct < 2; ++ct) {
                    bf16x8 b = ldsw(Bs, g * 32 + ct * 16 + lr, g8);
                    acc[g][0][ct] = __builtin_amdgcn_mfma_f32_16x16x32_bf16(a0, b, acc[g][0][ct], 0, 0, 0);
                    acc[g][1][ct] = __builtin_amdgcn_mfma_f32_16x16x32_bf16(a1, b, acc[g][1][ct], 0, 0, 0);
                }
            }
        }
        __syncthreads();
    }

    // epilogue: C/D layout col=lane&15, row=(lane>>4)*4+reg [m89/m91]
    #pragma unroll
    for (int ct = 0; ct < 2; ++ct) {
        const int j = j0 + ct * 16 + lr;
        const float br  = b_ih[j] + b_hh[j];
        const float bz  = b_ih[HDIM + j] + b_hh[HDIM + j];
        const float bn  = b_ih[2 * HDIM + j];
        const float bhn = b_hh[2 * HDIM + j];
        #pragma unroll
        for (int rt = 0; rt < 2; ++rt) {
            #pragma unroll
            for (int r = 0; r < 4; ++r) {
                const int row = m0 + wv * 32 + rt * 16 + lq * 4 + r;
                float rg = fsig(acc[0][rt][ct][r] + br);
                float zg = fsig(acc[1][rt][ct][r] + bz);
                float ng = ftanh(acc[2][rt][ct][r] + bn + rg * bhn);
                Hout[(size_t)row * 256 + coloff + j] = f2bf((1.0f - zg) * ng);
            }
        }
    }
}

// ---------------------------------------------------------------------------
// zgemm: Zc = h2 @ M16^T ([N,256] x [16,256] -> [N,10] fp32), LDS-staged A,
// B in registers. [within R9's ~30 us tail budget]
// ---------------------------------------------------------------------------
__global__ __launch_bounds__(256, 5) void zgemm(
    const ushort_t* __restrict__ A,    // h2 [N,256] bf16
    const ushort_t* __restrict__ M16,  // [16,256] bf16
    float* __restrict__ Zc)            // [N,10] fp32
{
    __shared__ ushort_t As[128 * 64];  // 16 KB
    const int tid = threadIdx.x;
    const int m0 = blockIdx.x * 128;
    const int wv = tid >> 6, lane = tid & 63;
    const int lr = lane & 15, lq = lane >> 4;
    const int tr = tid >> 3, tc = tid & 7;
    const int sc = ((tr + tc) & 7) << 3;

    bf16x8 bfrag[8];
    #pragma unroll
    for (int s = 0; s < 8; ++s)
        bfrag[s] = *(const bf16x8*)&M16[lr * 256 + s * 32 + lq * 8];

    f32x4 acc[2];
    #pragma unroll
    for (int e = 0; e < 4; ++e) { acc[0][e] = 0.0f; acc[1][e] = 0.0f; }

    for (int t = 0; t < 4; ++t) {
        const int k0 = t * 64;
        const ushort_t* ga = A + (size_t)(m0 + tr) * 256 + k0 + sc;
        #pragma unroll
        for (int i = 0; i < 4; ++i)
            gll16(ga + (size_t)i * 32 * 256, &As[(i * 256 + tid) * 8]);
        __syncthreads();
        #pragma unroll
        for (int kk = 0; kk < 64; kk += 32) {
            const int g8 = (kk >> 3) + lq;
            bf16x8 a0 = ldsw(As, wv * 32 + lr, g8);
            bf16x8 a1 = ldsw(As, wv * 32 + 16 + lr, g8);
            bf16x8 b = bfrag[t * 2 + (kk >> 5)];
            acc[0] = __builtin_amdgcn_mfma_f32_16x16x32_bf16(a0, b, acc[0], 0, 0, 0);
            acc[1] = __builtin_amdgcn_mfma_f32_16x16x32_bf16(a1, b, acc[1], 0, 0, 0);
        }
        __syncthreads();
    }

    if (lr < 10) {
        #pragma unroll
        for (int rt = 0; rt < 2; ++rt)
            #pragma unroll
            for (int r = 0; r < 4; ++r) {
                int row = m0 + wv * 32 + rt * 16 + lq * 4 + r;
                Zc[(size_t)row * 10 + lr] = acc[rt][r];
            }
    }
}

// ---------------------------------------------------------------------------
// st5: fused double GCN aggregation (5-point stencil) + bias corrections.
// ---------------------------------------------------------------------------
__device__ __forceinline__ float dcoef(int i) {
    return (i == 0 || i == N_NODES - 1) ? 0.70710678118654752f : 0.57735026918962576f;
}
__global__ __launch_bounds__(256) void st5(
    const float* __restrict__ z, float* __restrict__ out,
    const float* __restrict__ cc)
{
    int idx = blockIdx.x * 256 + threadIdx.x;   // N*16
    int i = idx >> 4, c = idx & 15;
    if (c >= 10) return;
    float d_i = dcoef(i);
    float accv = 0.0f, dsum = d_i;
    #pragma unroll
    for (int oj = -1; oj <= 1; ++oj) {
        int j = i + oj;
        if (j < 0 || j >= N_NODES) continue;
        float dj = dcoef(j);
        if (oj != 0) dsum += dj;
        float wj = 0.0f;
        #pragma unroll
        for (int ok = -1; ok <= 1; ++ok) {
            int k = j + ok;
            if (k < 0 || k >= N_NODES) continue;
            wj += dcoef(k) * z[(size_t)k * 10 + c];
        }
        accv += dj * dj * wj;
    }
    out[(size_t)i * 10 + c] = d_i * accv + d_i * dsum * cc[c] + cc[16 + c];
}

extern "C" void kernel_launch(void* const* d_in, const int* in_sizes, int n_in,
                              void* d_out, int out_size, void* d_ws, size_t ws_size,
                              hipStream_t stream) {
    const float* x     = (const float*)d_in[0];
    const float* w_f1  = (const float*)d_in[1];
    const float* bi_f1 = (const float*)d_in[2];
    const float* bh_f1 = (const float*)d_in[3];
    const float* w_b1  = (const float*)d_in[4];
    const float* bi_b1 = (const float*)d_in[5];
    const float* bh_b1 = (const float*)d_in[6];
    const float* w_f2  = (const float*)d_in[7];
    const float* bi_f2 = (const float*)d_in[8];
    const float* bh_f2 = (const float*)d_in[9];
    const float* w_b2  = (const float*)d_in[10];
    const float* bi_b2 = (const float*)d_in[11];
    const float* bh_b2 = (const float*)d_in[12];
    const float* w_g1  = (const float*)d_in[13];
    const float* b_g1  = (const float*)d_in[14];
    const float* w_g2  = (const float*)d_in[15];
    const float* b_g2  = (const float*)d_in[16];
    const float* w_fc  = (const float*)d_in[17];
    const float* b_fc  = (const float*)d_in[18];

    char* ws = (char*)d_ws;
    ushort_t* h1   = (ushort_t*)(ws);                    // [N,256] bf16, dies after layer2
    ushort_t* xb   = (ushort_t*)(ws + 67108864);         // [N,128] bf16 x, dies after layer1
    ushort_t* h2   = (ushort_t*)(ws + 67108864);         // [N,256] bf16, overwrites dead xb
    float*    Zc   = (float*)(ws);                       // [N,10] fp32, reuse dead h1
    ushort_t* PWF1 = (ushort_t*)(ws + 134217728);        // [384,128] bf16
    ushort_t* PWB1 = PWF1 + 49152;
    ushort_t* PWF2 = PWB1 + 49152;                       // [384,256] bf16
    ushort_t* PWB2 = PWF2 + 98304;
    ushort_t* M16  = PWB2 + 98304;                       // [16,256] bf16
    float*    cc   = (float*)(M16 + 4096);               // cc1[0..9], cc2[16..25]

    prep_weights<<<1152, 256, 0, stream>>>(w_f1, w_b1, w_f2, w_b2,
                                           PWF1, PWB1, PWF2, PWB2);
    prep_M<<<1, 256, 0, stream>>>(w_g1, b_g1, w_g2, b_g2, w_fc, b_fc, M16, cc);
    xconv<<<N_NODES * 16 / 256, 256, 0, stream>>>(x, xb);

    gru_gemm2<128><<<N_NODES / 128 * 8, 256, 0, stream>>>(
        xb, PWF1, PWB1, bi_f1, bh_f1, bi_b1, bh_b1, h1);
    gru_gemm2<256><<<N_NODES / 128 * 8, 256, 0, stream>>>(
        h1, PWF2, PWB2, bi_f2, bh_f2, bi_b2, bh_b2, h2);

    zgemm<<<N_NODES / 128, 256, 0, stream>>>(h2, M16, Zc);
    st5<<<N_NODES * 16 / 256, 256, 0, stream>>>(Zc, (float*)d_out, cc);
}